// Round 7
// baseline (1572.995 us; speedup 1.0000x reference)
//
#include <hip/hip_runtime.h>
#include <hip/hip_bf16.h>

#define B_ 8
#define T_ 2048
#define D_ 1024
#define W_ 64
#define LN_EPS 1e-5f
#define LOG2E 1.4426950408889634f

typedef __attribute__((ext_vector_type(8))) short bf16x8;
typedef __attribute__((ext_vector_type(4))) float f32x4;
typedef __attribute__((ext_vector_type(2))) float f32x2;
typedef unsigned short ushort_t;

__device__ __forceinline__ ushort_t f32_to_bf16(float f) {
    union { float ff; unsigned u; } c; c.ff = f;
    unsigned r = (c.u + 0x7fffu + ((c.u >> 16) & 1u)) >> 16;
    return (ushort_t)r;
}
__device__ __forceinline__ float bf16_to_f32(ushort_t h) {
    union { unsigned u; float f; } c; c.u = ((unsigned)h) << 16; return c.f;
}
__device__ __forceinline__ float tanh_fast(float x) {
    float xx = fminf(fmaxf(x, -20.f), 20.f);
    float e = __expf(2.f * xx);
    return 1.f - 2.f / (e + 1.f);
}
__device__ __forceinline__ float readlane_f(float v, int l) {
    return __int_as_float(__builtin_amdgcn_readlane(__float_as_int(v), l));
}
// DPP-based add with immediate control (template => constant integer)
template <int CTRL>
__device__ __forceinline__ float dpp_add(float x) {
    int y = __builtin_amdgcn_update_dpp(0, __float_as_int(x), CTRL, 0xf, 0xf, true);
    return x + __int_as_float(y);
}
// Packed pair reduction: one DPP chain reduces both components.
template <int CTRL>
__device__ __forceinline__ f32x2 pk_dpp_add(f32x2 v) {
    f32x2 t;
    t.x = __int_as_float(__builtin_amdgcn_update_dpp(0, __float_as_int(v.x), CTRL, 0xf, 0xf, true));
    t.y = __int_as_float(__builtin_amdgcn_update_dpp(0, __float_as_int(v.y), CTRL, 0xf, 0xf, true));
    return v + t;
}
__device__ __forceinline__ f32x2 sum64_pair(f32x2 v) {
    v = pk_dpp_add<0x111>(v);  // row_shr:1
    v = pk_dpp_add<0x112>(v);  // row_shr:2
    v = pk_dpp_add<0x114>(v);  // row_shr:4
    v = pk_dpp_add<0x118>(v);  // row_shr:8
    v = pk_dpp_add<0x142>(v);  // row_bcast:15
    v = pk_dpp_add<0x143>(v);  // row_bcast:31 -> lane63 = totals
    return v;
}
__device__ __forceinline__ f32x2 lo2(f32x4 v) { return __builtin_shufflevector(v, v, 0, 1); }
__device__ __forceinline__ f32x2 hi2(f32x4 v) { return __builtin_shufflevector(v, v, 2, 3); }

// ---------- K0: feature -> bf16 ----------
__global__ void cvt_feat(const float* __restrict__ f, ushort_t* __restrict__ o, int n) {
    int i = blockIdx.x * blockDim.x + threadIdx.x;
    if (i < n) o[i] = f32_to_bf16(f[i]);
}

// ---------- K1: wqT[n][k] = bf16(wq[k][n]) ----------
__global__ void cvt_wqT(const float* __restrict__ wq, ushort_t* __restrict__ o) {
    __shared__ float tile[64][65];
    int bi = blockIdx.x, bj = blockIdx.y, tid = threadIdx.x;
    int c = tid & 63, r4 = tid >> 6;
    for (int it = 0; it < 16; ++it) {
        int r = it * 4 + r4;
        tile[r][c] = wq[(size_t)(bi * 64 + r) * D_ + bj * 64 + c];
    }
    __syncthreads();
    for (int it = 0; it < 16; ++it) {
        int r = it * 4 + r4;
        o[(size_t)(bj * 64 + r) * D_ + bi * 64 + c] = f32_to_bf16(tile[c][r]);
    }
}

// ---------- K2: qw = (featbf @ wqT^T + wq_b) * w2_w * log2(e)  (MFMA bf16) ----------
__global__ __launch_bounds__(256) void gemm_qw(
        const ushort_t* __restrict__ A, const ushort_t* __restrict__ BT,
        const float* __restrict__ wqb, const float* __restrict__ w2w,
        float* __restrict__ out) {
    const int K = 1024;
    __shared__ ushort_t Al[128][48];
    __shared__ ushort_t Bl[64][48];
    int tid = threadIdx.x;
    int lane = tid & 63, wv = tid >> 6;
    int wm = wv >> 1, wn = wv & 1;
    int m0 = blockIdx.x * 128, n0 = blockIdx.y * 64;
    int mrow = lane & 15, quad = lane >> 4;
    f32x4 acc[4][2] = {};
    for (int k0 = 0; k0 < K; k0 += 32) {
#pragma unroll
        for (int rep = 0; rep < 2; ++rep) {
            int idx = rep * 256 + tid;
            int r = idx >> 2, cp = (idx & 3) * 8;
            *(bf16x8*)&Al[r][cp] = *(const bf16x8*)&A[(size_t)(m0 + r) * K + k0 + cp];
        }
        {
            int r = tid >> 2, cp = (tid & 3) * 8;
            *(bf16x8*)&Bl[r][cp] = *(const bf16x8*)&BT[(size_t)(n0 + r) * K + k0 + cp];
        }
        __syncthreads();
        bf16x8 af[4], bfr[2];
#pragma unroll
        for (int ms = 0; ms < 4; ++ms) af[ms] = *(bf16x8*)&Al[wm * 64 + ms * 16 + mrow][quad * 8];
#pragma unroll
        for (int ns = 0; ns < 2; ++ns) bfr[ns] = *(bf16x8*)&Bl[wn * 32 + ns * 16 + mrow][quad * 8];
#pragma unroll
        for (int ms = 0; ms < 4; ++ms)
#pragma unroll
            for (int ns = 0; ns < 2; ++ns)
                acc[ms][ns] = __builtin_amdgcn_mfma_f32_16x16x32_bf16(af[ms], bfr[ns], acc[ms][ns], 0, 0, 0);
        __syncthreads();
    }
#pragma unroll
    for (int ns = 0; ns < 2; ++ns) {
        int n = n0 + wn * 32 + ns * 16 + mrow;
        float scale = w2w[n] * LOG2E, bias = wqb[n];
#pragma unroll
        for (int ms = 0; ms < 4; ++ms) {
#pragma unroll
            for (int r = 0; r < 4; ++r) {
                int m = m0 + wm * 64 + ms * 16 + quad * 4 + r;
                out[(size_t)m * D_ + n] = (acc[ms][ns][r] + bias) * scale;
            }
        }
    }
}

// ---------- K3: transpose first 64 feature rows: fT32/fTh/fTl [b][d][w] ----------
__global__ void featT_kernel(const float* __restrict__ feat, float* __restrict__ fT32,
                             ushort_t* __restrict__ fTh, ushort_t* __restrict__ fTl) {
    __shared__ float tile[64][65];
    int d0 = blockIdx.x * 64, b = blockIdx.y, tid = threadIdx.x;
    int c = tid & 63, r4 = tid >> 6;
#pragma unroll
    for (int it = 0; it < 16; ++it) {
        int r = it * 4 + r4;
        tile[r][c] = feat[((size_t)b * T_ + r) * D_ + d0 + c];
    }
    __syncthreads();
#pragma unroll
    for (int it = 0; it < 16; ++it) {
        int r = it * 4 + r4;
        float v = tile[c][r];
        size_t o = ((size_t)b * D_ + d0 + r) * 64 + c;
        fT32[o] = v;
        ushort_t h = f32_to_bf16(v);
        fTh[o] = h;
        fTl[o] = f32_to_bf16(v - bf16_to_f32(h));
    }
}

// ---------- K4: S0[b][t][w] = qw[b][t]·F0[b][w]  (fp32, stored as bf16 hi/lo) ----------
__global__ __launch_bounds__(256) void s0_gemm(
        const float* __restrict__ qw, const float* __restrict__ fT32,
        ushort_t* __restrict__ S0h, ushort_t* __restrict__ S0l) {
    __shared__ float As[64][17];
    __shared__ float Bs[16][65];
    int b = blockIdx.y;
    int t0 = 64 + blockIdx.x * 64;
    int tx = threadIdx.x & 15, ty = threadIdx.x >> 4;
    float acc[4][4] = {};
    for (int k0 = 0; k0 < D_; k0 += 16) {
#pragma unroll
        for (int i = 0; i < 4; ++i) {
            int idx = i * 256 + threadIdx.x;
            int r = idx >> 4, c = idx & 15;
            As[r][c] = qw[((size_t)b * T_ + t0 + r) * D_ + k0 + c];
        }
#pragma unroll
        for (int i = 0; i < 4; ++i) {
            int idx = i * 256 + threadIdx.x;
            int r = idx >> 6, c = idx & 63;
            Bs[r][c] = fT32[((size_t)b * D_ + k0 + r) * 64 + c];
        }
        __syncthreads();
#pragma unroll
        for (int kk = 0; kk < 16; ++kk)
#pragma unroll
            for (int i = 0; i < 4; ++i)
#pragma unroll
                for (int j = 0; j < 4; ++j)
                    acc[i][j] = fmaf(As[ty * 4 + i][kk], Bs[kk][tx * 4 + j], acc[i][j]);
        __syncthreads();
    }
#pragma unroll
    for (int i = 0; i < 4; ++i)
#pragma unroll
        for (int j = 0; j < 4; ++j) {
            float sc = acc[i][j];
            ushort_t h = f32_to_bf16(sc);
            size_t o = ((size_t)b * T_ + t0 + ty * 4 + i) * 64 + tx * 4 + j;
            S0h[o] = h;
            S0l[o] = f32_to_bf16(sc - bf16_to_f32(h));
        }
}

// ---------- K5: sequential core, 1 wave per batch ----------
// SGPR-broadcast matvec: e[slot] is broadcast via v_readlane (constant lane
// index) into SGPRs and consumed directly by v_fma (one SGPR operand is
// legal).  The alpha-row LDS write->read roundtrip is GONE from the step
// loop; the e-row is still written to ALPH once per step, but only the
// Gamma sections (16+ steps later) read it.  Per-step LDS: e-write, nxt2v
// read, u_new column write, rtot write -- all off the critical chain.
__global__ __launch_bounds__(64, 1) void core_kernel(
        const ushort_t* __restrict__ S0h, const ushort_t* __restrict__ S0l,
        float* __restrict__ gamma) {
    const int b = blockIdx.x;
    const int lane = threadIdx.x;
    const int n16 = lane & 15, quad = lane >> 4;
    __shared__ float ULDS[64 * 67];          // Z: row=pos, col=slot
    __shared__ __align__(16) float ALPH[64 * 68];  // e matrix; col64 = rtot
    __shared__ __align__(16) float B1L[16 * 68];   // sub-block Gamma staging
    __shared__ ushort_t CH[64 * 72];         // C rows   [slot][basis]  bf16 hi
    __shared__ ushort_t CL[64 * 72];
    __shared__ ushort_t CWTh[64 * 72];       // C^T rows [basis][slot]  bf16 hi
    __shared__ ushort_t CWTl[64 * 72];

#pragma unroll
    for (int jj = 0; jj < 72; ++jj) {
        ushort_t idv = (jj == lane) ? (ushort_t)0x3F80 : (ushort_t)0;
        CH[lane * 72 + jj] = idv;  CL[lane * 72 + jj] = 0;
        CWTh[lane * 72 + jj] = idv; CWTl[lane * 72 + jj] = 0;
    }
    // single wave: DS pipe is in-order per wave; no barriers needed.

#pragma unroll 1
    for (int p = 0; p < 31; ++p) {
        const int t0 = 64 + (p << 6);

        // ---- Lpre = S0sup @ C^T via split-bf16 MFMA -> ULDS ----
        {
            bf16x8 Bh[4][2], Blo[4][2];
#pragma unroll
            for (int nt = 0; nt < 4; ++nt)
#pragma unroll
                for (int kt = 0; kt < 2; ++kt) {
                    int a = (nt * 16 + n16) * 72 + kt * 32 + quad * 8;
                    Bh[nt][kt] = *(const bf16x8*)&CH[a];
                    Blo[nt][kt] = *(const bf16x8*)&CL[a];
                }
#pragma unroll
            for (int mt = 0; mt < 4; ++mt) {
                bf16x8 Ah[2], Alo2[2];
#pragma unroll
                for (int kt = 0; kt < 2; ++kt) {
                    size_t a = ((size_t)b * T_ + t0 + mt * 16 + n16) * 64 + kt * 32 + quad * 8;
                    Ah[kt] = *(const bf16x8*)&S0h[a];
                    Alo2[kt] = *(const bf16x8*)&S0l[a];
                }
                f32x4 acc[4] = {};
#pragma unroll
                for (int nt = 0; nt < 4; ++nt)
#pragma unroll
                    for (int kt = 0; kt < 2; ++kt) {
                        acc[nt] = __builtin_amdgcn_mfma_f32_16x16x32_bf16(Ah[kt], Bh[nt][kt], acc[nt], 0, 0, 0);
                        acc[nt] = __builtin_amdgcn_mfma_f32_16x16x32_bf16(Ah[kt], Blo[nt][kt], acc[nt], 0, 0, 0);
                        acc[nt] = __builtin_amdgcn_mfma_f32_16x16x32_bf16(Alo2[kt], Bh[nt][kt], acc[nt], 0, 0, 0);
                    }
#pragma unroll
                for (int nt = 0; nt < 4; ++nt)
#pragma unroll
                    for (int r = 0; r < 4; ++r)
                        ULDS[(mt * 16 + quad * 4 + r) * 67 + nt * 16 + n16] = acc[nt][r];
            }
        }

        // X (lane = time position, index = slot) as f32x2 pairs, constant-indexed
        f32x2 Xa2[8], Xb2[8], Xc2[8], Xd2[8];
#pragma unroll
        for (int l2 = 0; l2 < 8; ++l2) {
            Xa2[l2].x = ULDS[lane * 67 + 2 * l2];
            Xa2[l2].y = ULDS[lane * 67 + 2 * l2 + 1];
            Xb2[l2].x = ULDS[lane * 67 + 16 + 2 * l2];
            Xb2[l2].y = ULDS[lane * 67 + 16 + 2 * l2 + 1];
            Xc2[l2].x = ULDS[lane * 67 + 32 + 2 * l2];
            Xc2[l2].y = ULDS[lane * 67 + 32 + 2 * l2 + 1];
            Xd2[l2].x = ULDS[lane * 67 + 48 + 2 * l2];
            Xd2[l2].y = ULDS[lane * 67 + 48 + 2 * l2 + 1];
        }
        float row = ULDS[lane];           // Z row 0 (fresh from Lpre)
        float nxt = ULDS[67 + lane];      // Z row 1

#pragma unroll 1
        for (int j = 0; j < 4; ++j) {     // ROLLED: runtime j, uniform branches
#pragma unroll
            for (int sl = 0; sl < 16; ++sl) {
                const int s = (j << 4) | sl;          // runtime via j
                const bool c61 = (sl <= 13);
                const bool c63 = (sl <= 14);
                bool do61 = c61 || (j < 3);           // s <= 61
                bool do63 = c63 || (j < 3);           // s < 63
                float e = __builtin_amdgcn_exp2f(row);   // logits pre-scaled by log2e
                ALPH[s * 68 + lane] = e;                 // for Gamma only (read 16+ steps later)
                float nxt2v = 0.f;
                if (do61) nxt2v = ULDS[(s + 2) * 67 + lane];
                // one packed DPP chain: {denominator, critical dot}
                f32x2 v; v.x = e; v.y = e * nxt;
                v = sum64_pair(v);
                float tot = readlane_f(v.x, 63) + 1.f;   // + 2^0 zero-row
                float cs  = readlane_f(v.y, 63);
                float r = __builtin_amdgcn_rcpf(tot);
                if (do63) {
                    float u_next = cs * r;               // u[s+1] (critical element)
                    // ---- SGPR-broadcast matvec: readlane(e, slot) -> v_fma ----
                    float a0 = 0.f, a1 = 0.f, a2 = 0.f, a3 = 0.f;
#pragma unroll
                    for (int q = 0; q < 8; ++q) {
                        a0 = fmaf(readlane_f(e, 2 * q),          Xa2[q].x, a0);
                        a1 = fmaf(readlane_f(e, 2 * q + 1),      Xa2[q].y, a1);
                        a2 = fmaf(readlane_f(e, 16 + 2 * q),     Xb2[q].x, a2);
                        a3 = fmaf(readlane_f(e, 16 + 2 * q + 1), Xb2[q].y, a3);
                        a0 = fmaf(readlane_f(e, 32 + 2 * q),     Xc2[q].x, a0);
                        a1 = fmaf(readlane_f(e, 32 + 2 * q + 1), Xc2[q].y, a1);
                        a2 = fmaf(readlane_f(e, 48 + 2 * q),     Xd2[q].x, a2);
                        a3 = fmaf(readlane_f(e, 48 + 2 * q + 1), Xd2[q].y, a3);
                    }
                    float u_new = ((a0 + a1) + (a2 + a3)) * r;
                    // X column update: col = s -> group by UNIFORM j branch, elem by const sl
                    if (j == 0)      { if (sl & 1) Xa2[sl >> 1].y = u_new; else Xa2[sl >> 1].x = u_new; }
                    else if (j == 1) { if (sl & 1) Xb2[sl >> 1].y = u_new; else Xb2[sl >> 1].x = u_new; }
                    else if (j == 2) { if (sl & 1) Xc2[sl >> 1].y = u_new; else Xc2[sl >> 1].x = u_new; }
                    else             { if (sl & 1) Xd2[sl >> 1].y = u_new; else Xd2[sl >> 1].x = u_new; }
                    if (lane > s) ULDS[lane * 67 + s] = u_new;
                    // register carry: patch stale col s of row s+2 via readlane
                    row = (lane == s) ? u_next : nxt;
                    if (do61) {
                        float pu = readlane_f(u_new, s + 2);
                        nxt = (lane == s) ? pu : nxt2v;
                    } else {
                        nxt = 0.f;
                    }
                }
                if (lane == 0) ALPH[s * 68 + 64] = r;    // stash rtot for Gamma
            }

            // ---- Gamma for sub-block j: B1 = A_J @ CW_preJ (MFMA), then correction ----
            {
                const int J0 = j << 4;
                float rrow = ALPH[(J0 + n16) * 68 + 64];   // rtot of this lane's row
                bf16x8 Aah[2], Aal[2];
#pragma unroll
                for (int kt = 0; kt < 2; ++kt) {
                    float v[8];
                    *(float4*)&v[0] = *(const float4*)&ALPH[(J0 + n16) * 68 + kt * 32 + quad * 8];
                    *(float4*)&v[4] = *(const float4*)&ALPH[(J0 + n16) * 68 + kt * 32 + quad * 8 + 4];
                    bf16x8 h, l;
#pragma unroll
                    for (int i = 0; i < 8; ++i) {
                        float val = v[i] * rrow;           // alpha = e * rtot
                        ushort_t hh = f32_to_bf16(val);
                        h[i] = (short)hh;
                        l[i] = (short)f32_to_bf16(val - bf16_to_f32(hh));
                    }
                    Aah[kt] = h; Aal[kt] = l;
                }
#pragma unroll
                for (int nt = 0; nt < 4; ++nt) {
                    f32x4 a = {};
#pragma unroll
                    for (int kt = 0; kt < 2; ++kt) {
                        bf16x8 bh = *(const bf16x8*)&CWTh[(nt * 16 + n16) * 72 + kt * 32 + quad * 8];
                        bf16x8 bl = *(const bf16x8*)&CWTl[(nt * 16 + n16) * 72 + kt * 32 + quad * 8];
                        a = __builtin_amdgcn_mfma_f32_16x16x32_bf16(Aah[kt], bh, a, 0, 0, 0);
                        a = __builtin_amdgcn_mfma_f32_16x16x32_bf16(Aah[kt], bl, a, 0, 0, 0);
                        a = __builtin_amdgcn_mfma_f32_16x16x32_bf16(Aal[kt], bh, a, 0, 0, 0);
                    }
#pragma unroll
                    for (int r = 0; r < 4; ++r)
                        B1L[(quad * 4 + r) * 68 + nt * 16 + n16] = a[r];
                }
                // triangular correction sweep (lane = basis column)
                float D[16];
#pragma unroll
                for (int sl = 0; sl < 16; ++sl) {
                    float corr = 0.f;
                    const float* arow = &ALPH[(J0 + sl) * 68 + J0];   // raw e values
#pragma unroll
                    for (int c = 0; c < 4; ++c) {
                        if (sl > 4 * c) {
                            float4 am = *(const float4*)&arow[4 * c];
                            if (sl > 4 * c + 0) corr = fmaf(am.x, D[4 * c + 0], corr);
                            if (sl > 4 * c + 1) corr = fmaf(am.y, D[4 * c + 1], corr);
                            if (sl > 4 * c + 2) corr = fmaf(am.z, D[4 * c + 2], corr);
                            if (sl > 4 * c + 3) corr = fmaf(am.w, D[4 * c + 3], corr);
                        }
                    }
                    float rsl = ALPH[(J0 + sl) * 68 + 64];            // broadcast rtot
                    float g = fmaf(rsl, corr, B1L[sl * 68 + lane]);
                    const int slot = J0 + sl;
                    float oldv = bf16_to_f32(CH[slot * 72 + lane]) + bf16_to_f32(CL[slot * 72 + lane]);
                    D[sl] = g - oldv;
                    gamma[((size_t)b * T_ + t0 + slot) * 64 + lane] = g;
                    ushort_t gh = f32_to_bf16(g);
                    ushort_t gl2 = f32_to_bf16(g - bf16_to_f32(gh));
                    CH[slot * 72 + lane] = gh;  CL[slot * 72 + lane] = gl2;
                    CWTh[lane * 72 + slot] = gh; CWTl[lane * 72 + slot] = gl2;
                }
            }
        }
    }
}

// ---------- K6: prologue rows 0..63: out = LN(tanh(f)*f + f) ----------
__global__ __launch_bounds__(256) void prologue_kernel(
        const float* __restrict__ feat, float* __restrict__ out,
        const float* __restrict__ lng, const float* __restrict__ lnb) {
    int b = blockIdx.y, t = blockIdx.x, tid = threadIdx.x;
    __shared__ float red[4][2];
    size_t base = ((size_t)b * T_ + t) * D_;
    float4 f4 = *(const float4*)&feat[base + tid * 4];
    float4 y;
    y.x = tanh_fast(f4.x) * f4.x + f4.x;
    y.y = tanh_fast(f4.y) * f4.y + f4.y;
    y.z = tanh_fast(f4.z) * f4.z + f4.z;
    y.w = tanh_fast(f4.w) * f4.w + f4.w;
    float s1 = y.x + y.y + y.z + y.w;
    float s2 = y.x * y.x + y.y * y.y + y.z * y.z + y.w * y.w;
#pragma unroll
    for (int m = 1; m < 64; m <<= 1) { s1 += __shfl_xor(s1, m, 64); s2 += __shfl_xor(s2, m, 64); }
    if ((tid & 63) == 0) { red[tid >> 6][0] = s1; red[tid >> 6][1] = s2; }
    __syncthreads();
    float mu = (red[0][0] + red[1][0] + red[2][0] + red[3][0]) * (1.f / D_);
    float m2 = (red[0][1] + red[1][1] + red[2][1] + red[3][1]) * (1.f / D_);
    float rv = rsqrtf(fmaxf(m2 - mu * mu, 0.f) + LN_EPS);
    float4 g4 = *(const float4*)&lng[tid * 4];
    float4 b4 = *(const float4*)&lnb[tid * 4];
    float4 o;
    o.x = (y.x - mu) * rv * g4.x + b4.x;
    o.y = (y.y - mu) * rv * g4.y + b4.y;
    o.z = (y.z - mu) * rv * g4.z + b4.z;
    o.w = (y.w - mu) * rv * g4.w + b4.w;
    *(float4*)&out[base + tid * 4] = o;
}

// ---------- K7: V = Γ @ F0 (split-bf16 MFMA) fused with gate + LayerNorm ----------
__global__ __launch_bounds__(256) void final_kernel(
        const float* __restrict__ gamma, const ushort_t* __restrict__ fTh,
        const ushort_t* __restrict__ fTl, const float* __restrict__ feat,
        const float* __restrict__ lng, const float* __restrict__ lnb,
        float* __restrict__ out) {
    const int b = blockIdx.y;
    const int t0 = 64 + blockIdx.x * 16;
    const int tid = threadIdx.x, lane = tid & 63, wv = tid >> 6;
    const int n16 = lane & 15, quad = lane >> 4;
    __shared__ float wsum[4][16][2];
    __shared__ float lnp[16][2];

    bf16x8 Ah[2], Alo[2];
    {
        const float* gr = &gamma[((size_t)b * T_ + t0 + n16) * 64];
#pragma unroll
        for (int kt = 0; kt < 2; ++kt) {
            float g[8];
            *(float4*)&g[0] = *(const float4*)&gr[kt * 32 + quad * 8];
            *(float4*)&g[4] = *(const float4*)&gr[kt * 32 + quad * 8 + 4];
            bf16x8 h, l;
#pragma unroll
            for (int i = 0; i < 8; ++i) {
                ushort_t hh = f32_to_bf16(g[i]);
                h[i] = (short)hh;
                l[i] = (short)f32_to_bf16(g[i] - bf16_to_f32(hh));
            }
            Ah[kt] = h; Alo[kt] = l;
        }
    }
    f32x4 acc[16];
#pragma unroll
    for (int j = 0; j < 16; ++j) {
        const int d = wv * 256 + j * 16 + n16;
        const ushort_t* fr = &fTh[((size_t)b * D_ + d) * 64];
        const ushort_t* fr2 = &fTl[((size_t)b * D_ + d) * 64];
        f32x4 a = {0.f, 0.f, 0.f, 0.f};
#pragma unroll
        for (int kt = 0; kt < 2; ++kt) {
            bf16x8 bh = *(const bf16x8*)&fr[kt * 32 + quad * 8];
            bf16x8 bl = *(const bf16x8*)&fr2[kt * 32 + quad * 8];
            a = __builtin_amdgcn_mfma_f32_16x16x32_bf16(Ah[kt], bh, a, 0, 0, 0);
            a = __builtin_amdgcn_mfma_f32_16x16x32_bf16(Ah[kt], bl, a, 0, 0, 0);
            a = __builtin_amdgcn_mfma_f32_16x16x32_bf16(Alo[kt], bh, a, 0, 0, 0);
        }
        acc[j] = a;
    }
    float s1[4] = {0.f, 0.f, 0.f, 0.f}, s2[4] = {0.f, 0.f, 0.f, 0.f};
#pragma unroll
    for (int j = 0; j < 16; ++j) {
        const int d = wv * 256 + j * 16 + n16;
#pragma unroll
        for (int r = 0; r < 4; ++r) {
            float f = feat[((size_t)b * T_ + t0 + quad * 4 + r) * D_ + d];
            float y = tanh_fast(acc[j][r]) * f + f;
            acc[j][r] = y;
            s1[r] += y;
            s2[r] += y * y;
        }
    }
#pragma unroll
    for (int m = 1; m < 16; m <<= 1)
#pragma unroll
        for (int r = 0; r < 4; ++r) { s1[r] += __shfl_xor(s1[r], m, 64); s2[r] += __shfl_xor(s2[r], m, 64); }
    if (n16 == 0) {
#pragma unroll
        for (int r = 0; r < 4; ++r) { wsum[wv][quad * 4 + r][0] = s1[r]; wsum[wv][quad * 4 + r][1] = s2[r]; }
    }
    __syncthreads();
    if (tid < 16) {
        float a = 0.f, c = 0.f;
#pragma unroll
        for (int w2 = 0; w2 < 4; ++w2) { a += wsum[w2][tid][0]; c += wsum[w2][tid][1]; }
        float mu = a * (1.f / D_);
        float var = c * (1.f / D_) - mu * mu;
        lnp[tid][0] = mu;
        lnp[tid][1] = rsqrtf(fmaxf(var, 0.f) + LN_EPS);
    }
    __syncthreads();
#pragma unroll
    for (int j = 0; j < 16; ++j) {
        const int d = wv * 256 + j * 16 + n16;
        float gd = lng[d], bd = lnb[d];
#pragma unroll
        for (int r = 0; r < 4; ++r) {
            int row = quad * 4 + r;
            out[((size_t)b * T_ + t0 + row) * D_ + d] = (acc[j][r] - lnp[row][0]) * lnp[row][1] * gd + bd;
        }
    }
}

extern "C" void kernel_launch(void* const* d_in, const int* in_sizes, int n_in,
                              void* d_out, int out_size, void* d_ws, size_t ws_size,
                              hipStream_t stream) {
    const float* feature = (const float*)d_in[0];
    const float* wq_w    = (const float*)d_in[1];
    const float* wq_b    = (const float*)d_in[2];
    const float* w2_w    = (const float*)d_in[3];
    // d_in[4] = w2_b: softmax-invariant, unused
    const float* ln_g    = (const float*)d_in[5];
    const float* ln_b    = (const float*)d_in[6];
    float* out = (float*)d_out;

    uint8_t* ws = (uint8_t*)d_ws;
    // phase-1 regions
    ushort_t* featbf = (ushort_t*)(ws);                       // 32 MB (dead after gemm_qw)
    ushort_t* wqT    = (ushort_t*)(ws + 32u * 1024 * 1024);   // 2 MB
    // phase-2 regions (alias featbf space)
    float*    gamma = (float*)(ws);                           // 4 MB
    ushort_t* S0h   = (ushort_t*)(ws + 4u * 1024 * 1024);     // 2 MB
    ushort_t* S0l   = (ushort_t*)(ws + 6u * 1024 * 1024);     // 2 MB
    float*    fT32  = (float*)(ws + 8u * 1024 * 1024);        // 2 MB
    ushort_t* fTh   = (ushort_t*)(ws + 10u * 1024 * 1024);    // 1 MB
    ushort_t* fTl   = (ushort_t*)(ws + 11u * 1024 * 1024);    // 1 MB

    const int ntot = B_ * T_ * D_;
    cvt_feat<<<(ntot + 255) / 256, 256, 0, stream>>>(feature, featbf, ntot);
    cvt_wqT<<<dim3(16, 16), 256, 0, stream>>>(wq_w, wqT);
    gemm_qw<<<dim3(128, 16), 256, 0, stream>>>(featbf, wqT, wq_b, w2_w, out);
    featT_kernel<<<dim3(16, 8), 256, 0, stream>>>(feature, fT32, fTh, fTl);
    s0_gemm<<<dim3(31, 8), 256, 0, stream>>>(out, fT32, S0h, S0l);
    core_kernel<<<8, 64, 0, stream>>>(S0h, S0l, gamma);
    prologue_kernel<<<dim3(64, 8), 256, 0, stream>>>(feature, out, ln_g, ln_b);
    final_kernel<<<dim3(124, 8), 256, 0, stream>>>(gamma, fTh, fTl, feature, ln_g, ln_b, out);
}

// Round 8
// 1336.464 us; speedup vs baseline: 1.1770x; 1.1770x over previous
//
#include <hip/hip_runtime.h>
#include <hip/hip_bf16.h>

#define B_ 8
#define T_ 2048
#define D_ 1024
#define W_ 64
#define LN_EPS 1e-5f
#define LOG2E 1.4426950408889634f

typedef __attribute__((ext_vector_type(8))) short bf16x8;
typedef __attribute__((ext_vector_type(4))) float f32x4;
typedef __attribute__((ext_vector_type(2))) float f32x2;
typedef unsigned short ushort_t;

__device__ __forceinline__ ushort_t f32_to_bf16(float f) {
    union { float ff; unsigned u; } c; c.ff = f;
    unsigned r = (c.u + 0x7fffu + ((c.u >> 16) & 1u)) >> 16;
    return (ushort_t)r;
}
__device__ __forceinline__ float bf16_to_f32(ushort_t h) {
    union { unsigned u; float f; } c; c.u = ((unsigned)h) << 16; return c.f;
}
__device__ __forceinline__ float tanh_fast(float x) {
    float xx = fminf(fmaxf(x, -20.f), 20.f);
    float e = __expf(2.f * xx);
    return 1.f - 2.f / (e + 1.f);
}
__device__ __forceinline__ float readlane_f(float v, int l) {
    return __int_as_float(__builtin_amdgcn_readlane(__float_as_int(v), l));
}
// DPP-based add with immediate control (template => constant integer)
template <int CTRL>
__device__ __forceinline__ float dpp_add(float x) {
    int y = __builtin_amdgcn_update_dpp(0, __float_as_int(x), CTRL, 0xf, 0xf, true);
    return x + __int_as_float(y);
}
// Packed pair reduction: one DPP chain reduces both components.
template <int CTRL>
__device__ __forceinline__ f32x2 pk_dpp_add(f32x2 v) {
    f32x2 t;
    t.x = __int_as_float(__builtin_amdgcn_update_dpp(0, __float_as_int(v.x), CTRL, 0xf, 0xf, true));
    t.y = __int_as_float(__builtin_amdgcn_update_dpp(0, __float_as_int(v.y), CTRL, 0xf, 0xf, true));
    return v + t;
}
__device__ __forceinline__ f32x2 sum64_pair(f32x2 v) {
    v = pk_dpp_add<0x111>(v);  // row_shr:1
    v = pk_dpp_add<0x112>(v);  // row_shr:2
    v = pk_dpp_add<0x114>(v);  // row_shr:4
    v = pk_dpp_add<0x118>(v);  // row_shr:8
    v = pk_dpp_add<0x142>(v);  // row_bcast:15
    v = pk_dpp_add<0x143>(v);  // row_bcast:31 -> lane63 = totals
    return v;
}
__device__ __forceinline__ f32x2 lo2(f32x4 v) { return __builtin_shufflevector(v, v, 0, 1); }
__device__ __forceinline__ f32x2 hi2(f32x4 v) { return __builtin_shufflevector(v, v, 2, 3); }

// ---------- K0: prep = cvt_feat (bf16) + wq transpose, one launch ----------
__global__ void prep_kernel(const float* __restrict__ f, ushort_t* __restrict__ o,
                            const float* __restrict__ wq, ushort_t* __restrict__ wqT) {
    __shared__ float tile[64][65];
    int tid = threadIdx.x;
    if (blockIdx.x < 32768) {
        // feature -> bf16, 2 elems/thread (16.7M elems / 512 = 32768 blocks exact)
        int i = blockIdx.x * 512 + tid * 2;
        float2 v = *(const float2*)&f[i];
        ushort2 w;
        w.x = f32_to_bf16(v.x);
        w.y = f32_to_bf16(v.y);
        *(ushort2*)&o[i] = w;
    } else {
        int bid = blockIdx.x - 32768;
        int bi = bid & 15, bj = bid >> 4;
        int c = tid & 63, r4 = tid >> 6;
        for (int it = 0; it < 16; ++it) {
            int r = it * 4 + r4;
            tile[r][c] = wq[(size_t)(bi * 64 + r) * D_ + bj * 64 + c];
        }
        __syncthreads();
        for (int it = 0; it < 16; ++it) {
            int r = it * 4 + r4;
            wqT[(size_t)(bj * 64 + r) * D_ + bi * 64 + c] = f32_to_bf16(tile[c][r]);
        }
    }
}

// ---------- K2: qw = (featbf @ wqT^T + wq_b) * w2_w * log2(e)  (MFMA bf16) ----------
__global__ __launch_bounds__(256) void gemm_qw(
        const ushort_t* __restrict__ A, const ushort_t* __restrict__ BT,
        const float* __restrict__ wqb, const float* __restrict__ w2w,
        float* __restrict__ out) {
    const int K = 1024;
    __shared__ ushort_t Al[128][48];
    __shared__ ushort_t Bl[64][48];
    int tid = threadIdx.x;
    int lane = tid & 63, wv = tid >> 6;
    int wm = wv >> 1, wn = wv & 1;
    int m0 = blockIdx.x * 128, n0 = blockIdx.y * 64;
    int mrow = lane & 15, quad = lane >> 4;
    f32x4 acc[4][2] = {};
    for (int k0 = 0; k0 < K; k0 += 32) {
#pragma unroll
        for (int rep = 0; rep < 2; ++rep) {
            int idx = rep * 256 + tid;
            int r = idx >> 2, cp = (idx & 3) * 8;
            *(bf16x8*)&Al[r][cp] = *(const bf16x8*)&A[(size_t)(m0 + r) * K + k0 + cp];
        }
        {
            int r = tid >> 2, cp = (tid & 3) * 8;
            *(bf16x8*)&Bl[r][cp] = *(const bf16x8*)&BT[(size_t)(n0 + r) * K + k0 + cp];
        }
        __syncthreads();
        bf16x8 af[4], bfr[2];
#pragma unroll
        for (int ms = 0; ms < 4; ++ms) af[ms] = *(bf16x8*)&Al[wm * 64 + ms * 16 + mrow][quad * 8];
#pragma unroll
        for (int ns = 0; ns < 2; ++ns) bfr[ns] = *(bf16x8*)&Bl[wn * 32 + ns * 16 + mrow][quad * 8];
#pragma unroll
        for (int ms = 0; ms < 4; ++ms)
#pragma unroll
            for (int ns = 0; ns < 2; ++ns)
                acc[ms][ns] = __builtin_amdgcn_mfma_f32_16x16x32_bf16(af[ms], bfr[ns], acc[ms][ns], 0, 0, 0);
        __syncthreads();
    }
#pragma unroll
    for (int ns = 0; ns < 2; ++ns) {
        int n = n0 + wn * 32 + ns * 16 + mrow;
        float scale = w2w[n] * LOG2E, bias = wqb[n];
#pragma unroll
        for (int ms = 0; ms < 4; ++ms) {
#pragma unroll
            for (int r = 0; r < 4; ++r) {
                int m = m0 + wm * 64 + ms * 16 + quad * 4 + r;
                out[(size_t)m * D_ + n] = (acc[ms][ns][r] + bias) * scale;
            }
        }
    }
}

// ---------- K3: first 64 feature rows -> fTh/fTl [b][d][w] (transposed)
//                                     + f0h/f0l [b][w][d] (row-major) ----------
__global__ void featT_kernel(const float* __restrict__ feat,
                             ushort_t* __restrict__ fTh, ushort_t* __restrict__ fTl,
                             ushort_t* __restrict__ f0h, ushort_t* __restrict__ f0l) {
    __shared__ float tile[64][65];
    int d0 = blockIdx.x * 64, b = blockIdx.y, tid = threadIdx.x;
    int c = tid & 63, r4 = tid >> 6;
#pragma unroll
    for (int it = 0; it < 16; ++it) {
        int r = it * 4 + r4;
        float v = feat[((size_t)b * T_ + r) * D_ + d0 + c];
        tile[r][c] = v;
        ushort_t h = f32_to_bf16(v);
        size_t o0 = ((size_t)b * 64 + r) * D_ + d0 + c;
        f0h[o0] = h;
        f0l[o0] = f32_to_bf16(v - bf16_to_f32(h));
    }
    __syncthreads();
#pragma unroll
    for (int it = 0; it < 16; ++it) {
        int r = it * 4 + r4;
        float v = tile[c][r];
        size_t o = ((size_t)b * D_ + d0 + r) * 64 + c;
        ushort_t h = f32_to_bf16(v);
        fTh[o] = h;
        fTl[o] = f32_to_bf16(v - bf16_to_f32(h));
    }
}

// ---------- K4: S0[b][t][w] = qw[b][t]·F0[b][w]  via split-bf16 MFMA ----------
__global__ __launch_bounds__(256) void s0_gemm(
        const float* __restrict__ qw, const ushort_t* __restrict__ f0h,
        const ushort_t* __restrict__ f0l,
        ushort_t* __restrict__ S0h, ushort_t* __restrict__ S0l) {
    const int b = blockIdx.y;
    const int t0 = 64 + blockIdx.x * 64;
    const int tid = threadIdx.x, lane = tid & 63, wv = tid >> 6;
    const int n16 = lane & 15, quad = lane >> 4;
    const float* qrow = &qw[((size_t)b * T_ + t0 + wv * 16 + n16) * D_];
    f32x4 acc[4] = {};
#pragma unroll 4
    for (int k0 = 0; k0 < D_; k0 += 32) {
        float a8[8];
        *(float4*)&a8[0] = *(const float4*)&qrow[k0 + quad * 8];
        *(float4*)&a8[4] = *(const float4*)&qrow[k0 + quad * 8 + 4];
        bf16x8 ah, al;
#pragma unroll
        for (int i = 0; i < 8; ++i) {
            ushort_t hh = f32_to_bf16(a8[i]);
            ah[i] = (short)hh;
            al[i] = (short)f32_to_bf16(a8[i] - bf16_to_f32(hh));
        }
#pragma unroll
        for (int nt = 0; nt < 4; ++nt) {
            const size_t fo = ((size_t)b * 64 + nt * 16 + n16) * D_ + k0 + quad * 8;
            bf16x8 bh = *(const bf16x8*)&f0h[fo];
            bf16x8 bl = *(const bf16x8*)&f0l[fo];
            acc[nt] = __builtin_amdgcn_mfma_f32_16x16x32_bf16(ah, bh, acc[nt], 0, 0, 0);
            acc[nt] = __builtin_amdgcn_mfma_f32_16x16x32_bf16(ah, bl, acc[nt], 0, 0, 0);
            acc[nt] = __builtin_amdgcn_mfma_f32_16x16x32_bf16(al, bh, acc[nt], 0, 0, 0);
        }
    }
#pragma unroll
    for (int nt = 0; nt < 4; ++nt)
#pragma unroll
        for (int r = 0; r < 4; ++r) {
            float sc = acc[nt][r];
            ushort_t h = f32_to_bf16(sc);
            size_t o2 = ((size_t)b * T_ + t0 + wv * 16 + quad * 4 + r) * 64 + nt * 16 + n16;
            S0h[o2] = h;
            S0l[o2] = f32_to_bf16(sc - bf16_to_f32(h));
        }
}

// ---------- K5: sequential core, 1 wave per batch (frozen R6 best: 1050us) ----------
__global__ __launch_bounds__(64, 1) void core_kernel(
        const ushort_t* __restrict__ S0h, const ushort_t* __restrict__ S0l,
        float* __restrict__ gamma) {
    const int b = blockIdx.x;
    const int lane = threadIdx.x;
    const int n16 = lane & 15, quad = lane >> 4;
    __shared__ float ULDS[64 * 67];          // Z: row=pos, col=slot
    __shared__ __align__(16) float ALPH[64 * 68];  // e matrix; col64 = rtot
    __shared__ __align__(16) float B1L[16 * 68];   // sub-block Gamma staging
    __shared__ ushort_t CH[64 * 72];         // C rows   [slot][basis]  bf16 hi
    __shared__ ushort_t CL[64 * 72];
    __shared__ ushort_t CWTh[64 * 72];       // C^T rows [basis][slot]  bf16 hi
    __shared__ ushort_t CWTl[64 * 72];

#pragma unroll
    for (int jj = 0; jj < 72; ++jj) {
        ushort_t idv = (jj == lane) ? (ushort_t)0x3F80 : (ushort_t)0;
        CH[lane * 72 + jj] = idv;  CL[lane * 72 + jj] = 0;
        CWTh[lane * 72 + jj] = idv; CWTl[lane * 72 + jj] = 0;
    }
    // single wave: DS pipe is in-order per wave; no barriers needed.

#pragma unroll 1
    for (int p = 0; p < 31; ++p) {
        const int t0 = 64 + (p << 6);

        // ---- Lpre = S0sup @ C^T via split-bf16 MFMA -> ULDS ----
        {
            bf16x8 Bh[4][2], Blo[4][2];
#pragma unroll
            for (int nt = 0; nt < 4; ++nt)
#pragma unroll
                for (int kt = 0; kt < 2; ++kt) {
                    int a = (nt * 16 + n16) * 72 + kt * 32 + quad * 8;
                    Bh[nt][kt] = *(const bf16x8*)&CH[a];
                    Blo[nt][kt] = *(const bf16x8*)&CL[a];
                }
#pragma unroll
            for (int mt = 0; mt < 4; ++mt) {
                bf16x8 Ah[2], Alo2[2];
#pragma unroll
                for (int kt = 0; kt < 2; ++kt) {
                    size_t a = ((size_t)b * T_ + t0 + mt * 16 + n16) * 64 + kt * 32 + quad * 8;
                    Ah[kt] = *(const bf16x8*)&S0h[a];
                    Alo2[kt] = *(const bf16x8*)&S0l[a];
                }
                f32x4 acc[4] = {};
#pragma unroll
                for (int nt = 0; nt < 4; ++nt)
#pragma unroll
                    for (int kt = 0; kt < 2; ++kt) {
                        acc[nt] = __builtin_amdgcn_mfma_f32_16x16x32_bf16(Ah[kt], Bh[nt][kt], acc[nt], 0, 0, 0);
                        acc[nt] = __builtin_amdgcn_mfma_f32_16x16x32_bf16(Ah[kt], Blo[nt][kt], acc[nt], 0, 0, 0);
                        acc[nt] = __builtin_amdgcn_mfma_f32_16x16x32_bf16(Alo2[kt], Bh[nt][kt], acc[nt], 0, 0, 0);
                    }
#pragma unroll
                for (int nt = 0; nt < 4; ++nt)
#pragma unroll
                    for (int r = 0; r < 4; ++r)
                        ULDS[(mt * 16 + quad * 4 + r) * 67 + nt * 16 + n16] = acc[nt][r];
            }
        }

        // X (lane = time position, index = slot) as f32x2 pairs, constant-indexed
        f32x2 Xa2[8], Xb2[8], Xc2[8], Xd2[8];
#pragma unroll
        for (int l2 = 0; l2 < 8; ++l2) {
            Xa2[l2].x = ULDS[lane * 67 + 2 * l2];
            Xa2[l2].y = ULDS[lane * 67 + 2 * l2 + 1];
            Xb2[l2].x = ULDS[lane * 67 + 16 + 2 * l2];
            Xb2[l2].y = ULDS[lane * 67 + 16 + 2 * l2 + 1];
            Xc2[l2].x = ULDS[lane * 67 + 32 + 2 * l2];
            Xc2[l2].y = ULDS[lane * 67 + 32 + 2 * l2 + 1];
            Xd2[l2].x = ULDS[lane * 67 + 48 + 2 * l2];
            Xd2[l2].y = ULDS[lane * 67 + 48 + 2 * l2 + 1];
        }
        float row = ULDS[lane];           // Z row 0 (fresh from Lpre)
        float nxt = ULDS[67 + lane];      // Z row 1

#pragma unroll 1
        for (int j = 0; j < 4; ++j) {     // ROLLED: runtime j, uniform branches
#pragma unroll
            for (int sl = 0; sl < 16; ++sl) {
                const int s = (j << 4) | sl;          // runtime via j
                const bool c61 = (sl <= 13);
                const bool c63 = (sl <= 14);
                bool do61 = c61 || (j < 3);           // s <= 61
                bool do63 = c63 || (j < 3);           // s < 63
                float e = __builtin_amdgcn_exp2f(row);   // logits pre-scaled by log2e
                ALPH[s * 68 + lane] = e;                 // raw e (div deferred)
                f32x4 A[16];
                if (do63) {
#pragma unroll
                    for (int i = 0; i < 16; ++i)
                        A[i] = *(const f32x4*)&ALPH[s * 68 + i * 4];
                }
                // read row s+2 BEFORE this step's u_new write; stale col s
                // patched from registers below.
                float nxt2v = 0.f;
                if (do61) nxt2v = ULDS[(s + 2) * 67 + lane];
                // one packed DPP chain: {denominator, critical dot}
                f32x2 v; v.x = e; v.y = e * nxt;
                v = sum64_pair(v);
                float tot = readlane_f(v.x, 63) + 1.f;   // + 2^0 zero-row
                float cs  = readlane_f(v.y, 63);
                float r = __builtin_amdgcn_rcpf(tot);
                if (do63) {
                    float u_next = cs * r;               // u[s+1] (critical element)
                    // bulk matvec on packed pairs (v_pk_fma_f32)
                    f32x2 acc0 = {0.f, 0.f}, acc1 = {0.f, 0.f}, acc2 = {0.f, 0.f}, acc3 = {0.f, 0.f};
#pragma unroll
                    for (int i2 = 0; i2 < 4; ++i2) {
                        f32x4 aa = A[i2];
                        acc0 = __builtin_elementwise_fma(lo2(aa), Xa2[2 * i2], acc0);
                        acc1 = __builtin_elementwise_fma(hi2(aa), Xa2[2 * i2 + 1], acc1);
                        f32x4 ab = A[4 + i2];
                        acc2 = __builtin_elementwise_fma(lo2(ab), Xb2[2 * i2], acc2);
                        acc3 = __builtin_elementwise_fma(hi2(ab), Xb2[2 * i2 + 1], acc3);
                        f32x4 ac = A[8 + i2];
                        acc0 = __builtin_elementwise_fma(lo2(ac), Xc2[2 * i2], acc0);
                        acc1 = __builtin_elementwise_fma(hi2(ac), Xc2[2 * i2 + 1], acc1);
                        f32x4 ad = A[12 + i2];
                        acc2 = __builtin_elementwise_fma(lo2(ad), Xd2[2 * i2], acc2);
                        acc3 = __builtin_elementwise_fma(hi2(ad), Xd2[2 * i2 + 1], acc3);
                    }
                    f32x2 u2 = (acc0 + acc1) + (acc2 + acc3);
                    float u_new = (u2.x + u2.y) * r;
                    // X column update: col = s -> group by UNIFORM j branch, elem by const sl
                    if (j == 0)      { if (sl & 1) Xa2[sl >> 1].y = u_new; else Xa2[sl >> 1].x = u_new; }
                    else if (j == 1) { if (sl & 1) Xb2[sl >> 1].y = u_new; else Xb2[sl >> 1].x = u_new; }
                    else if (j == 2) { if (sl & 1) Xc2[sl >> 1].y = u_new; else Xc2[sl >> 1].x = u_new; }
                    else             { if (sl & 1) Xd2[sl >> 1].y = u_new; else Xd2[sl >> 1].x = u_new; }
                    if (lane > s) ULDS[lane * 67 + s] = u_new;
                    // register carry: patch stale col s of row s+2 via readlane
                    row = (lane == s) ? u_next : nxt;
                    if (do61) {
                        float pu = readlane_f(u_new, s + 2);
                        nxt = (lane == s) ? pu : nxt2v;
                    } else {
                        nxt = 0.f;
                    }
                }
                if (lane == 0) ALPH[s * 68 + 64] = r;    // stash rtot for Gamma
            }

            // ---- Gamma for sub-block j: B1 = A_J @ CW_preJ (MFMA), then correction ----
            {
                const int J0 = j << 4;
                float rrow = ALPH[(J0 + n16) * 68 + 64];   // rtot of this lane's row
                bf16x8 Aah[2], Aal[2];
#pragma unroll
                for (int kt = 0; kt < 2; ++kt) {
                    float v[8];
                    *(float4*)&v[0] = *(const float4*)&ALPH[(J0 + n16) * 68 + kt * 32 + quad * 8];
                    *(float4*)&v[4] = *(const float4*)&ALPH[(J0 + n16) * 68 + kt * 32 + quad * 8 + 4];
                    bf16x8 h, l;
#pragma unroll
                    for (int i = 0; i < 8; ++i) {
                        float val = v[i] * rrow;           // alpha = e * rtot
                        ushort_t hh = f32_to_bf16(val);
                        h[i] = (short)hh;
                        l[i] = (short)f32_to_bf16(val - bf16_to_f32(hh));
                    }
                    Aah[kt] = h; Aal[kt] = l;
                }
#pragma unroll
                for (int nt = 0; nt < 4; ++nt) {
                    f32x4 a = {};
#pragma unroll
                    for (int kt = 0; kt < 2; ++kt) {
                        bf16x8 bh = *(const bf16x8*)&CWTh[(nt * 16 + n16) * 72 + kt * 32 + quad * 8];
                        bf16x8 bl = *(const bf16x8*)&CWTl[(nt * 16 + n16) * 72 + kt * 32 + quad * 8];
                        a = __builtin_amdgcn_mfma_f32_16x16x32_bf16(Aah[kt], bh, a, 0, 0, 0);
                        a = __builtin_amdgcn_mfma_f32_16x16x32_bf16(Aah[kt], bl, a, 0, 0, 0);
                        a = __builtin_amdgcn_mfma_f32_16x16x32_bf16(Aal[kt], bh, a, 0, 0, 0);
                    }
#pragma unroll
                    for (int r = 0; r < 4; ++r)
                        B1L[(quad * 4 + r) * 68 + nt * 16 + n16] = a[r];
                }
                // triangular correction sweep (lane = basis column)
                float D[16];
#pragma unroll
                for (int sl = 0; sl < 16; ++sl) {
                    float corr = 0.f;
                    const float* arow = &ALPH[(J0 + sl) * 68 + J0];   // raw e values
#pragma unroll
                    for (int c = 0; c < 4; ++c) {
                        if (sl > 4 * c) {
                            float4 am = *(const float4*)&arow[4 * c];
                            if (sl > 4 * c + 0) corr = fmaf(am.x, D[4 * c + 0], corr);
                            if (sl > 4 * c + 1) corr = fmaf(am.y, D[4 * c + 1], corr);
                            if (sl > 4 * c + 2) corr = fmaf(am.z, D[4 * c + 2], corr);
                            if (sl > 4 * c + 3) corr = fmaf(am.w, D[4 * c + 3], corr);
                        }
                    }
                    float rsl = ALPH[(J0 + sl) * 68 + 64];            // broadcast rtot
                    float g = fmaf(rsl, corr, B1L[sl * 68 + lane]);
                    const int slot = J0 + sl;
                    float oldv = bf16_to_f32(CH[slot * 72 + lane]) + bf16_to_f32(CL[slot * 72 + lane]);
                    D[sl] = g - oldv;
                    gamma[((size_t)b * T_ + t0 + slot) * 64 + lane] = g;
                    ushort_t gh = f32_to_bf16(g);
                    ushort_t gl2 = f32_to_bf16(g - bf16_to_f32(gh));
                    CH[slot * 72 + lane] = gh;  CL[slot * 72 + lane] = gl2;
                    CWTh[lane * 72 + slot] = gh; CWTl[lane * 72 + slot] = gl2;
                }
            }
        }
    }
}

// ---------- K7: V = Γ @ F0 (split-bf16 MFMA) fused with gate + LayerNorm,
//                plus prologue rows 0..63 handled by blocks bx >= 124 ----------
__global__ __launch_bounds__(256) void final_kernel(
        const float* __restrict__ gamma, const ushort_t* __restrict__ fTh,
        const ushort_t* __restrict__ fTl, const float* __restrict__ feat,
        const float* __restrict__ lng, const float* __restrict__ lnb,
        float* __restrict__ out) {
    const int b = blockIdx.y;
    const int tid = threadIdx.x;
    __shared__ float wsum[4][16][2];
    __shared__ float lnp[16][2];
    __shared__ float red[4][2];

    if (blockIdx.x >= 124) {
        // ---- prologue path: one row t in 0..63, out = LN(tanh(f)*f + f) ----
        int t = blockIdx.x - 124;
        size_t base = ((size_t)b * T_ + t) * D_;
        float4 f4 = *(const float4*)&feat[base + tid * 4];
        float4 y;
        y.x = tanh_fast(f4.x) * f4.x + f4.x;
        y.y = tanh_fast(f4.y) * f4.y + f4.y;
        y.z = tanh_fast(f4.z) * f4.z + f4.z;
        y.w = tanh_fast(f4.w) * f4.w + f4.w;
        float s1 = y.x + y.y + y.z + y.w;
        float s2 = y.x * y.x + y.y * y.y + y.z * y.z + y.w * y.w;
#pragma unroll
        for (int m = 1; m < 64; m <<= 1) { s1 += __shfl_xor(s1, m, 64); s2 += __shfl_xor(s2, m, 64); }
        if ((tid & 63) == 0) { red[tid >> 6][0] = s1; red[tid >> 6][1] = s2; }
        __syncthreads();
        float mu = (red[0][0] + red[1][0] + red[2][0] + red[3][0]) * (1.f / D_);
        float m2 = (red[0][1] + red[1][1] + red[2][1] + red[3][1]) * (1.f / D_);
        float rv = rsqrtf(fmaxf(m2 - mu * mu, 0.f) + LN_EPS);
        float4 g4 = *(const float4*)&lng[tid * 4];
        float4 b4 = *(const float4*)&lnb[tid * 4];
        float4 o;
        o.x = (y.x - mu) * rv * g4.x + b4.x;
        o.y = (y.y - mu) * rv * g4.y + b4.y;
        o.z = (y.z - mu) * rv * g4.z + b4.z;
        o.w = (y.w - mu) * rv * g4.w + b4.w;
        *(float4*)&out[base + tid * 4] = o;
        return;
    }

    const int t0 = 64 + blockIdx.x * 16;
    const int lane = tid & 63, wv = tid >> 6;
    const int n16 = lane & 15, quad = lane >> 4;

    bf16x8 Ah[2], Alo[2];
    {
        const float* gr = &gamma[((size_t)b * T_ + t0 + n16) * 64];
#pragma unroll
        for (int kt = 0; kt < 2; ++kt) {
            float g[8];
            *(float4*)&g[0] = *(const float4*)&gr[kt * 32 + quad * 8];
            *(float4*)&g[4] = *(const float4*)&gr[kt * 32 + quad * 8 + 4];
            bf16x8 h, l;
#pragma unroll
            for (int i = 0; i < 8; ++i) {
                ushort_t hh = f32_to_bf16(g[i]);
                h[i] = (short)hh;
                l[i] = (short)f32_to_bf16(g[i] - bf16_to_f32(hh));
            }
            Ah[kt] = h; Alo[kt] = l;
        }
    }
    f32x4 acc[16];
#pragma unroll
    for (int j = 0; j < 16; ++j) {
        const int d = wv * 256 + j * 16 + n16;
        const ushort_t* fr = &fTh[((size_t)b * D_ + d) * 64];
        const ushort_t* fr2 = &fTl[((size_t)b * D_ + d) * 64];
        f32x4 a = {0.f, 0.f, 0.f, 0.f};
#pragma unroll
        for (int kt = 0; kt < 2; ++kt) {
            bf16x8 bh = *(const bf16x8*)&fr[kt * 32 + quad * 8];
            bf16x8 bl = *(const bf16x8*)&fr2[kt * 32 + quad * 8];
            a = __builtin_amdgcn_mfma_f32_16x16x32_bf16(Ah[kt], bh, a, 0, 0, 0);
            a = __builtin_amdgcn_mfma_f32_16x16x32_bf16(Ah[kt], bl, a, 0, 0, 0);
            a = __builtin_amdgcn_mfma_f32_16x16x32_bf16(Alo[kt], bh, a, 0, 0, 0);
        }
        acc[j] = a;
    }
    float s1[4] = {0.f, 0.f, 0.f, 0.f}, s2[4] = {0.f, 0.f, 0.f, 0.f};
#pragma unroll
    for (int j = 0; j < 16; ++j) {
        const int d = wv * 256 + j * 16 + n16;
#pragma unroll
        for (int r = 0; r < 4; ++r) {
            float f = feat[((size_t)b * T_ + t0 + quad * 4 + r) * D_ + d];
            float y = tanh_fast(acc[j][r]) * f + f;
            acc[j][r] = y;
            s1[r] += y;
            s2[r] += y * y;
        }
    }
#pragma unroll
    for (int m = 1; m < 16; m <<= 1)
#pragma unroll
        for (int r = 0; r < 4; ++r) { s1[r] += __shfl_xor(s1[r], m, 64); s2[r] += __shfl_xor(s2[r], m, 64); }
    if (n16 == 0) {
#pragma unroll
        for (int r = 0; r < 4; ++r) { wsum[wv][quad * 4 + r][0] = s1[r]; wsum[wv][quad * 4 + r][1] = s2[r]; }
    }
    __syncthreads();
    if (tid < 16) {
        float a = 0.f, c = 0.f;
#pragma unroll
        for (int w2 = 0; w2 < 4; ++w2) { a += wsum[w2][tid][0]; c += wsum[w2][tid][1]; }
        float mu = a * (1.f / D_);
        float var = c * (1.f / D_) - mu * mu;
        lnp[tid][0] = mu;
        lnp[tid][1] = rsqrtf(fmaxf(var, 0.f) + LN_EPS);
    }
    __syncthreads();
#pragma unroll
    for (int j = 0; j < 16; ++j) {
        const int d = wv * 256 + j * 16 + n16;
        float gd = lng[d], bd = lnb[d];
#pragma unroll
        for (int r = 0; r < 4; ++r) {
            int row = quad * 4 + r;
            out[((size_t)b * T_ + t0 + row) * D_ + d] = (acc[j][r] - lnp[row][0]) * lnp[row][1] * gd + bd;
        }
    }
}

extern "C" void kernel_launch(void* const* d_in, const int* in_sizes, int n_in,
                              void* d_out, int out_size, void* d_ws, size_t ws_size,
                              hipStream_t stream) {
    const float* feature = (const float*)d_in[0];
    const float* wq_w    = (const float*)d_in[1];
    const float* wq_b    = (const float*)d_in[2];
    const float* w2_w    = (const float*)d_in[3];
    // d_in[4] = w2_b: softmax-invariant, unused
    const float* ln_g    = (const float*)d_in[5];
    const float* ln_b    = (const float*)d_in[6];
    float* out = (float*)d_out;

    uint8_t* ws = (uint8_t*)d_ws;
    // phase-1 regions
    ushort_t* featbf = (ushort_t*)(ws);                       // 32 MB (dead after gemm_qw)
    ushort_t* wqT    = (ushort_t*)(ws + 32u * 1024 * 1024);   // 2 MB
    // phase-2 regions (alias featbf space; all written after gemm_qw completes)
    float*    gamma = (float*)(ws);                           // 4 MB
    ushort_t* S0h   = (ushort_t*)(ws + 4u * 1024 * 1024);     // 2 MB
    ushort_t* S0l   = (ushort_t*)(ws + 6u * 1024 * 1024);     // 2 MB
    ushort_t* fTh   = (ushort_t*)(ws + 8u * 1024 * 1024);     // 1 MB
    ushort_t* fTl   = (ushort_t*)(ws + 9u * 1024 * 1024);     // 1 MB
    ushort_t* f0h   = (ushort_t*)(ws + 10u * 1024 * 1024);    // 1 MB
    ushort_t* f0l   = (ushort_t*)(ws + 11u * 1024 * 1024);    // 1 MB

    prep_kernel<<<33024, 256, 0, stream>>>(feature, featbf, wq_w, wqT);
    gemm_qw<<<dim3(128, 16), 256, 0, stream>>>(featbf, wqT, wq_b, w2_w, out);
    featT_kernel<<<dim3(16, 8), 256, 0, stream>>>(feature, fTh, fTl, f0h, f0l);
    s0_gemm<<<dim3(31, 8), 256, 0, stream>>>(out, f0h, f0l, S0h, S0l);
    core_kernel<<<8, 64, 0, stream>>>(S0h, S0l, gamma);
    final_kernel<<<dim3(188, 8), 256, 0, stream>>>(gamma, fTh, fTl, feature, ln_g, ln_b, out);
}

// Round 9
// 1144.780 us; speedup vs baseline: 1.3741x; 1.1674x over previous
//
#include <hip/hip_runtime.h>
#include <hip/hip_bf16.h>

#define B_ 8
#define T_ 2048
#define D_ 1024
#define W_ 64
#define LN_EPS 1e-5f
#define LOG2E 1.4426950408889634f

typedef __attribute__((ext_vector_type(8))) short bf16x8;
typedef __attribute__((ext_vector_type(4))) float f32x4;
typedef __attribute__((ext_vector_type(2))) float f32x2;
typedef unsigned short ushort_t;

__device__ __forceinline__ ushort_t f32_to_bf16(float f) {
    union { float ff; unsigned u; } c; c.ff = f;
    unsigned r = (c.u + 0x7fffu + ((c.u >> 16) & 1u)) >> 16;
    return (ushort_t)r;
}
__device__ __forceinline__ float bf16_to_f32(ushort_t h) {
    union { unsigned u; float f; } c; c.u = ((unsigned)h) << 16; return c.f;
}
__device__ __forceinline__ float tanh_fast(float x) {
    float xx = fminf(fmaxf(x, -20.f), 20.f);
    float e = __expf(2.f * xx);
    return 1.f - 2.f / (e + 1.f);
}
__device__ __forceinline__ float readlane_f(float v, int l) {
    return __int_as_float(__builtin_amdgcn_readlane(__float_as_int(v), l));
}
// DPP-based add with immediate control (template => constant integer)
template <int CTRL>
__device__ __forceinline__ float dpp_add(float x) {
    int y = __builtin_amdgcn_update_dpp(0, __float_as_int(x), CTRL, 0xf, 0xf, true);
    return x + __int_as_float(y);
}
// Packed pair reduction: one DPP chain reduces both components.
template <int CTRL>
__device__ __forceinline__ f32x2 pk_dpp_add(f32x2 v) {
    f32x2 t;
    t.x = __int_as_float(__builtin_amdgcn_update_dpp(0, __float_as_int(v.x), CTRL, 0xf, 0xf, true));
    t.y = __int_as_float(__builtin_amdgcn_update_dpp(0, __float_as_int(v.y), CTRL, 0xf, 0xf, true));
    return v + t;
}
__device__ __forceinline__ f32x2 sum64_pair(f32x2 v) {
    v = pk_dpp_add<0x111>(v);  // row_shr:1
    v = pk_dpp_add<0x112>(v);  // row_shr:2
    v = pk_dpp_add<0x114>(v);  // row_shr:4
    v = pk_dpp_add<0x118>(v);  // row_shr:8
    v = pk_dpp_add<0x142>(v);  // row_bcast:15
    v = pk_dpp_add<0x143>(v);  // row_bcast:31 -> lane63 = totals
    return v;
}
__device__ __forceinline__ f32x2 lo2(f32x4 v) { return __builtin_shufflevector(v, v, 0, 1); }
__device__ __forceinline__ f32x2 hi2(f32x4 v) { return __builtin_shufflevector(v, v, 2, 3); }

// ---------- K0: prep = cvt_feat (bf16) + wq transpose, one launch ----------
__global__ void prep_kernel(const float* __restrict__ f, ushort_t* __restrict__ o,
                            const float* __restrict__ wq, ushort_t* __restrict__ wqT) {
    __shared__ float tile[64][65];
    int tid = threadIdx.x;
    if (blockIdx.x < 32768) {
        int i = blockIdx.x * 512 + tid * 2;
        float2 v = *(const float2*)&f[i];
        ushort2 w;
        w.x = f32_to_bf16(v.x);
        w.y = f32_to_bf16(v.y);
        *(ushort2*)&o[i] = w;
    } else {
        int bid = blockIdx.x - 32768;
        int bi = bid & 15, bj = bid >> 4;
        int c = tid & 63, r4 = tid >> 6;
        for (int it = 0; it < 16; ++it) {
            int r = it * 4 + r4;
            tile[r][c] = wq[(size_t)(bi * 64 + r) * D_ + bj * 64 + c];
        }
        __syncthreads();
        for (int it = 0; it < 16; ++it) {
            int r = it * 4 + r4;
            wqT[(size_t)(bj * 64 + r) * D_ + bi * 64 + c] = f32_to_bf16(tile[c][r]);
        }
    }
}

// ---------- K2: qw = (featbf @ wqT^T + wq_b) * w2_w * log2(e)  (MFMA bf16) ----------
__global__ __launch_bounds__(256) void gemm_qw(
        const ushort_t* __restrict__ A, const ushort_t* __restrict__ BT,
        const float* __restrict__ wqb, const float* __restrict__ w2w,
        float* __restrict__ out) {
    const int K = 1024;
    __shared__ ushort_t Al[128][48];
    __shared__ ushort_t Bl[64][48];
    int tid = threadIdx.x;
    int lane = tid & 63, wv = tid >> 6;
    int wm = wv >> 1, wn = wv & 1;
    int m0 = blockIdx.x * 128, n0 = blockIdx.y * 64;
    int mrow = lane & 15, quad = lane >> 4;
    f32x4 acc[4][2] = {};
    for (int k0 = 0; k0 < K; k0 += 32) {
#pragma unroll
        for (int rep = 0; rep < 2; ++rep) {
            int idx = rep * 256 + tid;
            int r = idx >> 2, cp = (idx & 3) * 8;
            *(bf16x8*)&Al[r][cp] = *(const bf16x8*)&A[(size_t)(m0 + r) * K + k0 + cp];
        }
        {
            int r = tid >> 2, cp = (tid & 3) * 8;
            *(bf16x8*)&Bl[r][cp] = *(const bf16x8*)&BT[(size_t)(n0 + r) * K + k0 + cp];
        }
        __syncthreads();
        bf16x8 af[4], bfr[2];
#pragma unroll
        for (int ms = 0; ms < 4; ++ms) af[ms] = *(bf16x8*)&Al[wm * 64 + ms * 16 + mrow][quad * 8];
#pragma unroll
        for (int ns = 0; ns < 2; ++ns) bfr[ns] = *(bf16x8*)&Bl[wn * 32 + ns * 16 + mrow][quad * 8];
#pragma unroll
        for (int ms = 0; ms < 4; ++ms)
#pragma unroll
            for (int ns = 0; ns < 2; ++ns)
                acc[ms][ns] = __builtin_amdgcn_mfma_f32_16x16x32_bf16(af[ms], bfr[ns], acc[ms][ns], 0, 0, 0);
        __syncthreads();
    }
#pragma unroll
    for (int ns = 0; ns < 2; ++ns) {
        int n = n0 + wn * 32 + ns * 16 + mrow;
        float scale = w2w[n] * LOG2E, bias = wqb[n];
#pragma unroll
        for (int ms = 0; ms < 4; ++ms) {
#pragma unroll
            for (int r = 0; r < 4; ++r) {
                int m = m0 + wm * 64 + ms * 16 + quad * 4 + r;
                out[(size_t)m * D_ + n] = (acc[ms][ns][r] + bias) * scale;
            }
        }
    }
}

// ---------- K3: first 64 feature rows -> fTh/fTl [b][d][w] (transposed)
//                                     + f0h/f0l [b][w][d] (row-major) ----------
__global__ void featT_kernel(const float* __restrict__ feat,
                             ushort_t* __restrict__ fTh, ushort_t* __restrict__ fTl,
                             ushort_t* __restrict__ f0h, ushort_t* __restrict__ f0l) {
    __shared__ float tile[64][65];
    int d0 = blockIdx.x * 64, b = blockIdx.y, tid = threadIdx.x;
    int c = tid & 63, r4 = tid >> 6;
#pragma unroll
    for (int it = 0; it < 16; ++it) {
        int r = it * 4 + r4;
        float v = feat[((size_t)b * T_ + r) * D_ + d0 + c];
        tile[r][c] = v;
        ushort_t h = f32_to_bf16(v);
        size_t o0 = ((size_t)b * 64 + r) * D_ + d0 + c;
        f0h[o0] = h;
        f0l[o0] = f32_to_bf16(v - bf16_to_f32(h));
    }
    __syncthreads();
#pragma unroll
    for (int it = 0; it < 16; ++it) {
        int r = it * 4 + r4;
        float v = tile[c][r];
        size_t o = ((size_t)b * D_ + d0 + r) * 64 + c;
        ushort_t h = f32_to_bf16(v);
        fTh[o] = h;
        fTl[o] = f32_to_bf16(v - bf16_to_f32(h));
    }
}

// ---------- K4: S0[b][t][w] = qw[b][t]·F0[b][w]  via split-bf16 MFMA ----------
__global__ __launch_bounds__(256) void s0_gemm(
        const float* __restrict__ qw, const ushort_t* __restrict__ f0h,
        const ushort_t* __restrict__ f0l,
        ushort_t* __restrict__ S0h, ushort_t* __restrict__ S0l) {
    const int b = blockIdx.y;
    const int t0 = 64 + blockIdx.x * 64;
    const int tid = threadIdx.x, lane = tid & 63, wv = tid >> 6;
    const int n16 = lane & 15, quad = lane >> 4;
    const float* qrow = &qw[((size_t)b * T_ + t0 + wv * 16 + n16) * D_];
    f32x4 acc[4] = {};
#pragma unroll 4
    for (int k0 = 0; k0 < D_; k0 += 32) {
        float a8[8];
        *(float4*)&a8[0] = *(const float4*)&qrow[k0 + quad * 8];
        *(float4*)&a8[4] = *(const float4*)&qrow[k0 + quad * 8 + 4];
        bf16x8 ah, al;
#pragma unroll
        for (int i = 0; i < 8; ++i) {
            ushort_t hh = f32_to_bf16(a8[i]);
            ah[i] = (short)hh;
            al[i] = (short)f32_to_bf16(a8[i] - bf16_to_f32(hh));
        }
#pragma unroll
        for (int nt = 0; nt < 4; ++nt) {
            const size_t fo = ((size_t)b * 64 + nt * 16 + n16) * D_ + k0 + quad * 8;
            bf16x8 bh = *(const bf16x8*)&f0h[fo];
            bf16x8 bl = *(const bf16x8*)&f0l[fo];
            acc[nt] = __builtin_amdgcn_mfma_f32_16x16x32_bf16(ah, bh, acc[nt], 0, 0, 0);
            acc[nt] = __builtin_amdgcn_mfma_f32_16x16x32_bf16(ah, bl, acc[nt], 0, 0, 0);
            acc[nt] = __builtin_amdgcn_mfma_f32_16x16x32_bf16(al, bh, acc[nt], 0, 0, 0);
        }
    }
#pragma unroll
    for (int nt = 0; nt < 4; ++nt)
#pragma unroll
        for (int r = 0; r < 4; ++r) {
            float sc = acc[nt][r];
            ushort_t h = f32_to_bf16(sc);
            size_t o2 = ((size_t)b * T_ + t0 + wv * 16 + quad * 4 + r) * 64 + nt * 16 + n16;
            S0h[o2] = h;
            S0l[o2] = f32_to_bf16(sc - bf16_to_f32(h));
        }
}

// ---------- K5: sequential core, 2 waves per batch ----------
// Wave0 = unchanged R6 step loop (softmax chain + matvec).
// Wave1 = Gamma pipeline: slot j runs Gamma(j-1) concurrently with wave0's
// steps of sub-block j (Gamma touches only ALPH[j-1 rows]/CH/CWT/B1L, which
// wave0's steps never read/write); Gamma(3) runs in a dedicated tail slot.
// Lpre's 4 row-tiles are split 2/2 across the waves.  One __syncthreads()
// per sub-block slot keeps producer/consumer ordering.
__global__ __launch_bounds__(128, 1) void core_kernel(
        const ushort_t* __restrict__ S0h, const ushort_t* __restrict__ S0l,
        float* __restrict__ gamma) {
    const int b = blockIdx.x;
    const int tid = threadIdx.x;
    const int wid = tid >> 6;
    const int lane = tid & 63;
    const int n16 = lane & 15, quad = lane >> 4;
    __shared__ float ULDS[64 * 67];          // Z: row=pos, col=slot
    __shared__ __align__(16) float ALPH[64 * 68];  // e matrix; col64 = rtot
    __shared__ __align__(16) float B1L[16 * 68];   // sub-block Gamma staging
    __shared__ ushort_t CH[64 * 72];         // C rows   [slot][basis]  bf16 hi
    __shared__ ushort_t CL[64 * 72];
    __shared__ ushort_t CWTh[64 * 72];       // C^T rows [basis][slot]  bf16 hi
    __shared__ ushort_t CWTl[64 * 72];

    if (wid == 0) {
#pragma unroll
        for (int jj = 0; jj < 72; ++jj) {
            ushort_t idv = (jj == lane) ? (ushort_t)0x3F80 : (ushort_t)0;
            CH[lane * 72 + jj] = idv;  CL[lane * 72 + jj] = 0;
            CWTh[lane * 72 + jj] = idv; CWTl[lane * 72 + jj] = 0;
        }
    }
    __syncthreads();

#pragma unroll 1
    for (int p = 0; p < 31; ++p) {
        const int t0 = 64 + (p << 6);

        // ---- Gamma section (runtime jg), executed by wave1 ----
        auto gamma_sec = [&](int jg) {
            const int J0 = jg << 4;
            float rrow = ALPH[(J0 + n16) * 68 + 64];   // rtot of this lane's row
            bf16x8 Aah[2], Aal[2];
#pragma unroll
            for (int kt = 0; kt < 2; ++kt) {
                float v[8];
                *(float4*)&v[0] = *(const float4*)&ALPH[(J0 + n16) * 68 + kt * 32 + quad * 8];
                *(float4*)&v[4] = *(const float4*)&ALPH[(J0 + n16) * 68 + kt * 32 + quad * 8 + 4];
                bf16x8 h, l;
#pragma unroll
                for (int i = 0; i < 8; ++i) {
                    float val = v[i] * rrow;           // alpha = e * rtot
                    ushort_t hh = f32_to_bf16(val);
                    h[i] = (short)hh;
                    l[i] = (short)f32_to_bf16(val - bf16_to_f32(hh));
                }
                Aah[kt] = h; Aal[kt] = l;
            }
#pragma unroll
            for (int nt = 0; nt < 4; ++nt) {
                f32x4 a = {};
#pragma unroll
                for (int kt = 0; kt < 2; ++kt) {
                    bf16x8 bh = *(const bf16x8*)&CWTh[(nt * 16 + n16) * 72 + kt * 32 + quad * 8];
                    bf16x8 bl = *(const bf16x8*)&CWTl[(nt * 16 + n16) * 72 + kt * 32 + quad * 8];
                    a = __builtin_amdgcn_mfma_f32_16x16x32_bf16(Aah[kt], bh, a, 0, 0, 0);
                    a = __builtin_amdgcn_mfma_f32_16x16x32_bf16(Aah[kt], bl, a, 0, 0, 0);
                    a = __builtin_amdgcn_mfma_f32_16x16x32_bf16(Aal[kt], bh, a, 0, 0, 0);
                }
#pragma unroll
                for (int r = 0; r < 4; ++r)
                    B1L[(quad * 4 + r) * 68 + nt * 16 + n16] = a[r];
            }
            // triangular correction sweep (lane = basis column)
            float D[16];
#pragma unroll
            for (int sl = 0; sl < 16; ++sl) {
                float corr = 0.f;
                const float* arow = &ALPH[(J0 + sl) * 68 + J0];   // raw e values
#pragma unroll
                for (int c = 0; c < 4; ++c) {
                    if (sl > 4 * c) {
                        float4 am = *(const float4*)&arow[4 * c];
                        if (sl > 4 * c + 0) corr = fmaf(am.x, D[4 * c + 0], corr);
                        if (sl > 4 * c + 1) corr = fmaf(am.y, D[4 * c + 1], corr);
                        if (sl > 4 * c + 2) corr = fmaf(am.z, D[4 * c + 2], corr);
                        if (sl > 4 * c + 3) corr = fmaf(am.w, D[4 * c + 3], corr);
                    }
                }
                float rsl = ALPH[(J0 + sl) * 68 + 64];            // broadcast rtot
                float g = fmaf(rsl, corr, B1L[sl * 68 + lane]);
                const int slot = J0 + sl;
                float oldv = bf16_to_f32(CH[slot * 72 + lane]) + bf16_to_f32(CL[slot * 72 + lane]);
                D[sl] = g - oldv;
                gamma[((size_t)b * T_ + t0 + slot) * 64 + lane] = g;
                ushort_t gh = f32_to_bf16(g);
                ushort_t gl2 = f32_to_bf16(g - bf16_to_f32(gh));
                CH[slot * 72 + lane] = gh;  CL[slot * 72 + lane] = gl2;
                CWTh[lane * 72 + slot] = gh; CWTl[lane * 72 + slot] = gl2;
            }
        };

        // ---- Lpre = S0sup @ C^T via split-bf16 MFMA -> ULDS (mt split 2/2) ----
        {
            bf16x8 Bh[4][2], Blo[4][2];
#pragma unroll
            for (int nt = 0; nt < 4; ++nt)
#pragma unroll
                for (int kt = 0; kt < 2; ++kt) {
                    int a = (nt * 16 + n16) * 72 + kt * 32 + quad * 8;
                    Bh[nt][kt] = *(const bf16x8*)&CH[a];
                    Blo[nt][kt] = *(const bf16x8*)&CL[a];
                }
#pragma unroll
            for (int mi = 0; mi < 2; ++mi) {
                const int mt = wid * 2 + mi;
                bf16x8 Ah[2], Alo2[2];
#pragma unroll
                for (int kt = 0; kt < 2; ++kt) {
                    size_t a = ((size_t)b * T_ + t0 + mt * 16 + n16) * 64 + kt * 32 + quad * 8;
                    Ah[kt] = *(const bf16x8*)&S0h[a];
                    Alo2[kt] = *(const bf16x8*)&S0l[a];
                }
                f32x4 acc[4] = {};
#pragma unroll
                for (int nt = 0; nt < 4; ++nt)
#pragma unroll
                    for (int kt = 0; kt < 2; ++kt) {
                        acc[nt] = __builtin_amdgcn_mfma_f32_16x16x32_bf16(Ah[kt], Bh[nt][kt], acc[nt], 0, 0, 0);
                        acc[nt] = __builtin_amdgcn_mfma_f32_16x16x32_bf16(Ah[kt], Blo[nt][kt], acc[nt], 0, 0, 0);
                        acc[nt] = __builtin_amdgcn_mfma_f32_16x16x32_bf16(Alo2[kt], Bh[nt][kt], acc[nt], 0, 0, 0);
                    }
#pragma unroll
                for (int nt = 0; nt < 4; ++nt)
#pragma unroll
                    for (int r = 0; r < 4; ++r)
                        ULDS[(mt * 16 + quad * 4 + r) * 67 + nt * 16 + n16] = acc[nt][r];
            }
        }
        __syncthreads();

        // X (lane = time position, index = slot) as f32x2 pairs (wave0 only)
        f32x2 Xa2[8], Xb2[8], Xc2[8], Xd2[8];
        float row = 0.f, nxt = 0.f;
        if (wid == 0) {
#pragma unroll
            for (int l2 = 0; l2 < 8; ++l2) {
                Xa2[l2].x = ULDS[lane * 67 + 2 * l2];
                Xa2[l2].y = ULDS[lane * 67 + 2 * l2 + 1];
                Xb2[l2].x = ULDS[lane * 67 + 16 + 2 * l2];
                Xb2[l2].y = ULDS[lane * 67 + 16 + 2 * l2 + 1];
                Xc2[l2].x = ULDS[lane * 67 + 32 + 2 * l2];
                Xc2[l2].y = ULDS[lane * 67 + 32 + 2 * l2 + 1];
                Xd2[l2].x = ULDS[lane * 67 + 48 + 2 * l2];
                Xd2[l2].y = ULDS[lane * 67 + 48 + 2 * l2 + 1];
            }
            row = ULDS[lane];           // Z row 0 (fresh from Lpre)
            nxt = ULDS[67 + lane];      // Z row 1
        }

#pragma unroll 1
        for (int j = 0; j < 4; ++j) {     // slot j: wave0 steps(j) || wave1 Gamma(j-1)
            if (wid == 0) {
#pragma unroll
                for (int sl = 0; sl < 16; ++sl) {
                    const int s = (j << 4) | sl;          // runtime via j
                    const bool c61 = (sl <= 13);
                    const bool c63 = (sl <= 14);
                    bool do61 = c61 || (j < 3);           // s <= 61
                    bool do63 = c63 || (j < 3);           // s < 63
                    float e = __builtin_amdgcn_exp2f(row);   // logits pre-scaled by log2e
                    ALPH[s * 68 + lane] = e;                 // raw e (div deferred)
                    f32x4 A[16];
                    if (do63) {
#pragma unroll
                        for (int i = 0; i < 16; ++i)
                            A[i] = *(const f32x4*)&ALPH[s * 68 + i * 4];
                    }
                    // read row s+2 BEFORE this step's u_new write; stale col s
                    // patched from registers below.
                    float nxt2v = 0.f;
                    if (do61) nxt2v = ULDS[(s + 2) * 67 + lane];
                    // one packed DPP chain: {denominator, critical dot}
                    f32x2 v; v.x = e; v.y = e * nxt;
                    v = sum64_pair(v);
                    float tot = readlane_f(v.x, 63) + 1.f;   // + 2^0 zero-row
                    float cs  = readlane_f(v.y, 63);
                    float r = __builtin_amdgcn_rcpf(tot);
                    if (do63) {
                        float u_next = cs * r;               // u[s+1] (critical element)
                        // bulk matvec on packed pairs (v_pk_fma_f32)
                        f32x2 acc0 = {0.f, 0.f}, acc1 = {0.f, 0.f}, acc2 = {0.f, 0.f}, acc3 = {0.f, 0.f};
#pragma unroll
                        for (int i2 = 0; i2 < 4; ++i2) {
                            f32x4 aa = A[i2];
                            acc0 = __builtin_elementwise_fma(lo2(aa), Xa2[2 * i2], acc0);
                            acc1 = __builtin_elementwise_fma(hi2(aa), Xa2[2 * i2 + 1], acc1);
                            f32x4 ab = A[4 + i2];
                            acc2 = __builtin_elementwise_fma(lo2(ab), Xb2[2 * i2], acc2);
                            acc3 = __builtin_elementwise_fma(hi2(ab), Xb2[2 * i2 + 1], acc3);
                            f32x4 ac = A[8 + i2];
                            acc0 = __builtin_elementwise_fma(lo2(ac), Xc2[2 * i2], acc0);
                            acc1 = __builtin_elementwise_fma(hi2(ac), Xc2[2 * i2 + 1], acc1);
                            f32x4 ad = A[12 + i2];
                            acc2 = __builtin_elementwise_fma(lo2(ad), Xd2[2 * i2], acc2);
                            acc3 = __builtin_elementwise_fma(hi2(ad), Xd2[2 * i2 + 1], acc3);
                        }
                        f32x2 u2 = (acc0 + acc1) + (acc2 + acc3);
                        float u_new = (u2.x + u2.y) * r;
                        // X column update: col = s -> group by UNIFORM j branch, elem by const sl
                        if (j == 0)      { if (sl & 1) Xa2[sl >> 1].y = u_new; else Xa2[sl >> 1].x = u_new; }
                        else if (j == 1) { if (sl & 1) Xb2[sl >> 1].y = u_new; else Xb2[sl >> 1].x = u_new; }
                        else if (j == 2) { if (sl & 1) Xc2[sl >> 1].y = u_new; else Xc2[sl >> 1].x = u_new; }
                        else             { if (sl & 1) Xd2[sl >> 1].y = u_new; else Xd2[sl >> 1].x = u_new; }
                        if (lane > s) ULDS[lane * 67 + s] = u_new;
                        // register carry: patch stale col s of row s+2 via readlane
                        row = (lane == s) ? u_next : nxt;
                        if (do61) {
                            float pu = readlane_f(u_new, s + 2);
                            nxt = (lane == s) ? pu : nxt2v;
                        } else {
                            nxt = 0.f;
                        }
                    }
                    if (lane == 0) ALPH[s * 68 + 64] = r;    // stash rtot for Gamma
                }
            } else if (j >= 1) {
                gamma_sec(j - 1);
            }
            __syncthreads();
        }
        // tail slot: Gamma(3) on wave1 (wave0 idles at the barrier)
        if (wid == 1) gamma_sec(3);
        __syncthreads();
    }
}

// ---------- K7: V = Γ @ F0 (split-bf16 MFMA) fused with gate + LayerNorm,
//                plus prologue rows 0..63 handled by blocks bx >= 124 ----------
__global__ __launch_bounds__(256) void final_kernel(
        const float* __restrict__ gamma, const ushort_t* __restrict__ fTh,
        const ushort_t* __restrict__ fTl, const float* __restrict__ feat,
        const float* __restrict__ lng, const float* __restrict__ lnb,
        float* __restrict__ out) {
    const int b = blockIdx.y;
    const int tid = threadIdx.x;
    __shared__ float wsum[4][16][2];
    __shared__ float lnp[16][2];
    __shared__ float red[4][2];

    if (blockIdx.x >= 124) {
        // ---- prologue path: one row t in 0..63, out = LN(tanh(f)*f + f) ----
        int t = blockIdx.x - 124;
        size_t base = ((size_t)b * T_ + t) * D_;
        float4 f4 = *(const float4*)&feat[base + tid * 4];
        float4 y;
        y.x = tanh_fast(f4.x) * f4.x + f4.x;
        y.y = tanh_fast(f4.y) * f4.y + f4.y;
        y.z = tanh_fast(f4.z) * f4.z + f4.z;
        y.w = tanh_fast(f4.w) * f4.w + f4.w;
        float s1 = y.x + y.y + y.z + y.w;
        float s2 = y.x * y.x + y.y * y.y + y.z * y.z + y.w * y.w;
#pragma unroll
        for (int m = 1; m < 64; m <<= 1) { s1 += __shfl_xor(s1, m, 64); s2 += __shfl_xor(s2, m, 64); }
        if ((tid & 63) == 0) { red[tid >> 6][0] = s1; red[tid >> 6][1] = s2; }
        __syncthreads();
        float mu = (red[0][0] + red[1][0] + red[2][0] + red[3][0]) * (1.f / D_);
        float m2 = (red[0][1] + red[1][1] + red[2][1] + red[3][1]) * (1.f / D_);
        float rv = rsqrtf(fmaxf(m2 - mu * mu, 0.f) + LN_EPS);
        float4 g4 = *(const float4*)&lng[tid * 4];
        float4 b4 = *(const float4*)&lnb[tid * 4];
        float4 o;
        o.x = (y.x - mu) * rv * g4.x + b4.x;
        o.y = (y.y - mu) * rv * g4.y + b4.y;
        o.z = (y.z - mu) * rv * g4.z + b4.z;
        o.w = (y.w - mu) * rv * g4.w + b4.w;
        *(float4*)&out[base + tid * 4] = o;
        return;
    }

    const int t0 = 64 + blockIdx.x * 16;
    const int lane = tid & 63, wv = tid >> 6;
    const int n16 = lane & 15, quad = lane >> 4;

    bf16x8 Ah[2], Alo[2];
    {
        const float* gr = &gamma[((size_t)b * T_ + t0 + n16) * 64];
#pragma unroll
        for (int kt = 0; kt < 2; ++kt) {
            float g[8];
            *(float4*)&g[0] = *(const float4*)&gr[kt * 32 + quad * 8];
            *(float4*)&g[4] = *(const float4*)&gr[kt * 32 + quad * 8 + 4];
            bf16x8 h, l;
#pragma unroll
            for (int i = 0; i < 8; ++i) {
                ushort_t hh = f32_to_bf16(g[i]);
                h[i] = (short)hh;
                l[i] = (short)f32_to_bf16(g[i] - bf16_to_f32(hh));
            }
            Ah[kt] = h; Alo[kt] = l;
        }
    }
    f32x4 acc[16];
#pragma unroll
    for (int j = 0; j < 16; ++j) {
        const int d = wv * 256 + j * 16 + n16;
        const ushort_t* fr = &fTh[((size_t)b * D_ + d) * 64];
        const ushort_t* fr2 = &fTl[((size_t)b * D_ + d) * 64];
        f32x4 a = {0.f, 0.f, 0.f, 0.f};
#pragma unroll
        for (int kt = 0; kt < 2; ++kt) {
            bf16x8 bh = *(const bf16x8*)&fr[kt * 32 + quad * 8];
            bf16x8 bl = *(const bf16x8*)&fr2[kt * 32 + quad * 8];
            a = __builtin_amdgcn_mfma_f32_16x16x32_bf16(Ah[kt], bh, a, 0, 0, 0);
            a = __builtin_amdgcn_mfma_f32_16x16x32_bf16(Ah[kt], bl, a, 0, 0, 0);
            a = __builtin_amdgcn_mfma_f32_16x16x32_bf16(Alo[kt], bh, a, 0, 0, 0);
        }
        acc[j] = a;
    }
    float s1[4] = {0.f, 0.f, 0.f, 0.f}, s2[4] = {0.f, 0.f, 0.f, 0.f};
#pragma unroll
    for (int j = 0; j < 16; ++j) {
        const int d = wv * 256 + j * 16 + n16;
#pragma unroll
        for (int r = 0; r < 4; ++r) {
            float f = feat[((size_t)b * T_ + t0 + quad * 4 + r) * D_ + d];
            float y = tanh_fast(acc[j][r]) * f + f;
            acc[j][r] = y;
            s1[r] += y;
            s2[r] += y * y;
        }
    }
#pragma unroll
    for (int m = 1; m < 16; m <<= 1)
#pragma unroll
        for (int r = 0; r < 4; ++r) { s1[r] += __shfl_xor(s1[r], m, 64); s2[r] += __shfl_xor(s2[r], m, 64); }
    if (n16 == 0) {
#pragma unroll
        for (int r = 0; r < 4; ++r) { wsum[wv][quad * 4 + r][0] = s1[r]; wsum[wv][quad * 4 + r][1] = s2[r]; }
    }
    __syncthreads();
    if (tid < 16) {
        float a = 0.f, c = 0.f;
#pragma unroll
        for (int w2 = 0; w2 < 4; ++w2) { a += wsum[w2][tid][0]; c += wsum[w2][tid][1]; }
        float mu = a * (1.f / D_);
        float var = c * (1.f / D_) - mu * mu;
        lnp[tid][0] = mu;
        lnp[tid][1] = rsqrtf(fmaxf(var, 0.f) + LN_EPS);
    }
    __syncthreads();
#pragma unroll
    for (int j = 0; j < 16; ++j) {
        const int d = wv * 256 + j * 16 + n16;
        float gd = lng[d], bd = lnb[d];
#pragma unroll
        for (int r = 0; r < 4; ++r) {
            int row = quad * 4 + r;
            out[((size_t)b * T_ + t0 + row) * D_ + d] = (acc[j][r] - lnp[row][0]) * lnp[row][1] * gd + bd;
        }
    }
}

extern "C" void kernel_launch(void* const* d_in, const int* in_sizes, int n_in,
                              void* d_out, int out_size, void* d_ws, size_t ws_size,
                              hipStream_t stream) {
    const float* feature = (const float*)d_in[0];
    const float* wq_w    = (const float*)d_in[1];
    const float* wq_b    = (const float*)d_in[2];
    const float* w2_w    = (const float*)d_in[3];
    // d_in[4] = w2_b: softmax-invariant, unused
    const float* ln_g    = (const float*)d_in[5];
    const float* ln_b    = (const float*)d_in[6];
    float* out = (float*)d_out;

    uint8_t* ws = (uint8_t*)d_ws;
    // phase-1 regions
    ushort_t* featbf = (ushort_t*)(ws);                       // 32 MB (dead after gemm_qw)
    ushort_t* wqT    = (ushort_t*)(ws + 32u * 1024 * 1024);   // 2 MB
    // phase-2 regions (alias featbf space; all written after gemm_qw completes)
    float*    gamma = (float*)(ws);                           // 4 MB
    ushort_t* S0h   = (ushort_t*)(ws + 4u * 1024 * 1024);     // 2 MB
    ushort_t* S0l   = (ushort_t*)(ws + 6u * 1024 * 1024);     // 2 MB
    ushort_t* fTh   = (ushort_t*)(ws + 8u * 1024 * 1024);     // 1 MB
    ushort_t* fTl   = (ushort_t*)(ws + 9u * 1024 * 1024);     // 1 MB
    ushort_t* f0h   = (ushort_t*)(ws + 10u * 1024 * 1024);    // 1 MB
    ushort_t* f0l   = (ushort_t*)(ws + 11u * 1024 * 1024);    // 1 MB

    prep_kernel<<<33024, 256, 0, stream>>>(feature, featbf, wq_w, wqT);
    gemm_qw<<<dim3(128, 16), 256, 0, stream>>>(featbf, wqT, wq_b, w2_w, out);
    featT_kernel<<<dim3(16, 8), 256, 0, stream>>>(feature, fTh, fTl, f0h, f0l);
    s0_gemm<<<dim3(31, 8), 256, 0, stream>>>(out, f0h, f0l, S0h, S0l);
    core_kernel<<<8, 128, 0, stream>>>(S0h, S0l, gamma);
    final_kernel<<<dim3(188, 8), 256, 0, stream>>>(gamma, fTh, fTl, feature, ln_g, ln_b, out);
}